// Round 15
// baseline (784.132 us; speedup 1.0000x reference)
//
#include <hip/hip_runtime.h>

// Autoregressive FFNN. out[b,0]=0; t=1..511: mi=[x[b,t,:],pred]; h=relu(mi@W1+b1); pred=h@W2+b2.
// B=4096,T=512,F=63. R14: 512 WGs x 512 thr (8 waves), 8 batch rows/WG, bounds(512,2)
// (NOT 4 — R7/R12 died from the forced VGPR cap, not the concept). Natural VGPR ~<110
// (w63v deleted: pred injected into B-frag k=63 slot, f16) => HW fits 2 WGs/CU = 4
// waves/SIMD; two independent recurrence chains interleave per CU.
// f16 datapath; b1 as MFMA C-init; layer2 = 4 f16 MFMAs (replicated-row W2), 2 chains;
// packed x staging (1 float2 + cvt_pkrtz + ds_write_b32); raw lgkm-only barrier.

#define TT 512
#define FF 63
#define HID 1024
#define ROWS 8

typedef __attribute__((ext_vector_type(4))) float f32x4;
typedef __attribute__((ext_vector_type(4))) int i32x4;
typedef __attribute__((ext_vector_type(8))) _Float16 h16x8;

struct __attribute__((packed, aligned(4))) uf2 { float x, y; };

// LDS-visibility barrier WITHOUT the vmcnt(0) drain of __syncthreads.
__device__ __forceinline__ void lds_barrier() {
  asm volatile("s_waitcnt lgkmcnt(0)" ::: "memory");
  __builtin_amdgcn_s_barrier();
  asm volatile("" ::: "memory");
}

// pack relu(a),relu(b) -> 2xf16 (RTZ) as int
__device__ __forceinline__ int pkh(float a, float b) {
  auto h = __builtin_amdgcn_cvt_pkrtz(fmaxf(a, 0.f), fmaxf(b, 0.f));
  return __builtin_bit_cast(int, h);
}
// pack a,b -> 2xf16 (RTZ) as int
__device__ __forceinline__ int pk2h(float a, float b) {
  auto h = __builtin_amdgcn_cvt_pkrtz(a, b);
  return __builtin_bit_cast(int, h);
}

__global__ __launch_bounds__(512, 2)
void ffnn_ar_kernel(const float* __restrict__ x,
                    const float* __restrict__ W1,
                    const float* __restrict__ b1,
                    const float* __restrict__ W2,
                    const float* __restrict__ b2p,
                    float* __restrict__ out) {
  __shared__ __align__(16) _Float16 lds_A[2][16][72];  // f16 x-tiles; rows 8..15 zeroed once
  __shared__ __align__(16) float lds_part[2][16][12];  // [buf][batch c][wave w]

  const int tid  = threadIdx.x;
  const int lane = tid & 63;
  const int w    = tid >> 6;    // wave 0..7: hidden cols [128w, 128w+128)
  const int c    = lane & 15;   // batch column (C col) / frag row-id
  const int g    = lane >> 4;   // k-group
  const int br   = blockIdx.x * ROWS;

  // ---- one-time weights ----
  // bfr[i][ks]: A1-frag = W1^T (f16): lane (c,g) slot j = W1[ks*32+g*8+j][(w*8+i)*16+c]
  // k=63 slot holds W1[63][n]: multiplied by B's k=63 element = injected pred. 
  h16x8 bfr[8][2];
#pragma unroll
  for (int i = 0; i < 8; ++i) {
    const int n = (w * 8 + i) * 16 + c;
#pragma unroll
    for (int ks = 0; ks < 2; ++ks) {
      h16x8 f;
#pragma unroll
      for (int j = 0; j < 8; ++j) f[j] = (_Float16)W1[(ks * 32 + g * 8 + j) * HID + n];
      bfr[i][ks] = f;
    }
  }
  // b1v[i]: C-init, lane (c,g) reg q = b1[(w*8+i)*16 + g*4 + q]
  f32x4 b1v[8];
#pragma unroll
  for (int i = 0; i < 8; ++i) {
    const int nb = (w * 8 + i) * 16 + g * 4;
    b1v[i] = (f32x4){b1[nb], b1[nb + 1], b1[nb + 2], b1[nb + 3]};
  }
  // a2f[i2]: f16 A2-frag (rows replicated): slot j = W2[(w*8+2*i2+(j>>2))*16 + g*4 + (j&3)]
  h16x8 a2f[4];
#pragma unroll
  for (int i2 = 0; i2 < 4; ++i2) {
    h16x8 f;
#pragma unroll
    for (int j = 0; j < 8; ++j)
      f[j] = (_Float16)W2[(w * 8 + 2 * i2 + (j >> 2)) * 16 + g * 4 + (j & 3)];
    a2f[i2] = f;
  }
  const float b2 = b2p[0];
  const float b2w = (w == 0) ? b2 : 0.f;  // baked once via wave0's layer-2 chain-a C-init

  // ---- x staging: wave w stages batch row w (w<8 always true); packed 2 elems/lane ----
  const int sl = lane & 31;            // 0..31; lane31 packs (x62, 0) -> col63 = 0
  const bool sact = (lane < 32);       // lanes 0..31 of each wave stage
  const long rowbase = (long)(br + w) * (TT * FF);
  const bool full = (sl < 31);

  // prologue: zero rows 8..15 (both buffers; 36 dwords/row)
  if (tid < 288) {
    const int r  = 8 + tid / 36;
    const int cc = (tid % 36) * 2;
    *reinterpret_cast<unsigned*>(&lds_A[0][r][cc]) = 0u;
    *reinterpret_cast<unsigned*>(&lds_A[1][r][cc]) = 0u;
  }
  // stage x_1 -> buf1 (packed); part bufs = 0 (pred_0 = 0); out[:,0] = 0
  if (sact) {
    float xa, xb;
    if (full) { const uf2 v = *reinterpret_cast<const uf2*>(&x[rowbase + FF + 2 * sl]); xa = v.x; xb = v.y; }
    else      { xa = x[rowbase + FF + 62]; xb = 0.f; }
    *reinterpret_cast<int*>(&lds_A[1][w][2 * sl]) = pk2h(xa, xb);
  }
  if (tid < 384) reinterpret_cast<float*>(lds_part)[tid] = 0.f;
  if (tid < ROWS) out[(long)(br + tid) * TT] = 0.f;

  // 2 prefetch sets: S0 = x_2, S1 = x_3
  float s0a = 0.f, s0b = 0.f, s1a = 0.f, s1b = 0.f;
  if (sact) {
    if (full) {
      const uf2 v0 = *reinterpret_cast<const uf2*>(&x[rowbase + 2 * FF + 2 * sl]);
      const uf2 v1 = *reinterpret_cast<const uf2*>(&x[rowbase + 3 * FF + 2 * sl]);
      s0a = v0.x; s0b = v0.y; s1a = v1.x; s1b = v1.y;
    } else {
      s0a = x[rowbase + 2 * FF + 62];
      s1a = x[rowbase + 3 * FF + 62];
    }
  }

  lds_barrier();

#define STEP(T, CUR, SA, SB)                                                        \
  {                                                                                 \
    /* gather pred_{T-1}[batch c]: 2x ds_read_b128 + 7-add tree */                  \
    const f32x4 v0 = *reinterpret_cast<const f32x4*>(&lds_part[(CUR) ^ 1][c][0]);   \
    const f32x4 v1 = *reinterpret_cast<const f32x4*>(&lds_part[(CUR) ^ 1][c][4]);   \
    /* x frags (f16); xb0-MFMAs are pred-independent and cover gather latency */    \
    const h16x8 xb0 = *reinterpret_cast<const h16x8*>(&lds_A[CUR][c][g * 8]);       \
    h16x8 xb1 = *reinterpret_cast<const h16x8*>(&lds_A[CUR][c][32 + g * 8]);        \
    const float pc = ((v0[0] + v0[1]) + (v0[2] + v0[3])) +                          \
                     ((v1[0] + v1[1]) + (v1[2] + v1[3]));                           \
    if (g == 3) xb1[7] = (_Float16)pc;                                              \
    f32x4 acc[8];                                                                   \
    _Pragma("unroll") for (int i = 0; i < 8; ++i) {                                 \
      f32x4 z4 = __builtin_amdgcn_mfma_f32_16x16x32_f16(bfr[i][0], xb0, b1v[i], 0, 0, 0); \
      acc[i] = __builtin_amdgcn_mfma_f32_16x16x32_f16(bfr[i][1], xb1, z4, 0, 0, 0); \
    }                                                                               \
    if (w == 0 && g == 0 && c < ROWS) out[(long)(br + c) * TT + ((T) - 1)] = pc;    \
    /* stage x_{T+1} (packed); prefetch x_{T+3} (stays in flight across barrier) */ \
    if (sact) *reinterpret_cast<int*>(&lds_A[(CUR) ^ 1][w][2 * sl]) = pk2h(SA, SB); \
    {                                                                               \
      const int tp = ((T) + 3 < TT) ? (T) + 3 : TT - 1;                             \
      if (sact) {                                                                   \
        if (full) { const uf2 v = *reinterpret_cast<const uf2*>(&x[rowbase + (long)tp * FF + 2 * sl]); \
                    SA = v.x; SB = v.y; }                                           \
        else      { SA = x[rowbase + (long)tp * FF + 62]; }                         \
      }                                                                             \
    }                                                                               \
    /* h = relu(z) packed f16 (b1 in C-init); layer2 = 4 MFMAs, 2 chains */         \
    f32x4 p2a = {b2w, b2w, b2w, b2w};                                               \
    f32x4 p2b = {0.f, 0.f, 0.f, 0.f};                                               \
    _Pragma("unroll") for (int i2 = 0; i2 < 4; ++i2) {                              \
      const f32x4 u = acc[2 * i2], v = acc[2 * i2 + 1];                             \
      const h16x8 hf = __builtin_bit_cast(h16x8, (i32x4){                           \
          pkh(u[0], u[1]), pkh(u[2], u[3]), pkh(v[0], v[1]), pkh(v[2], v[3])});     \
      if (i2 & 1)                                                                   \
        p2b = __builtin_amdgcn_mfma_f32_16x16x32_f16(a2f[i2], hf, p2b, 0, 0, 0);    \
      else                                                                          \
        p2a = __builtin_amdgcn_mfma_f32_16x16x32_f16(a2f[i2], hf, p2a, 0, 0, 0);    \
    }                                                                               \
    if (g == 0) lds_part[CUR][c][w] = p2a[0] + p2b[0];                              \
    lds_barrier();                                                                  \
  }

#pragma unroll 1
  for (int t = 1; t + 1 < TT; t += 2) {
    STEP(t, 1, s0a, s0b)
    STEP(t + 1, 0, s1a, s1b)
  }
  STEP(TT - 1, 1, s0a, s0b)  // t = 511 (CUR=1, writes lds_part[1])

  // final: pred_511 from lds_part[1]
  {
    const f32x4 v0 = *reinterpret_cast<const f32x4*>(&lds_part[1][c][0]);
    const f32x4 v1 = *reinterpret_cast<const f32x4*>(&lds_part[1][c][4]);
    const float pc = ((v0[0] + v0[1]) + (v0[2] + v0[3])) +
                     ((v1[0] + v1[1]) + (v1[2] + v1[3]));
    if (w == 0 && g == 0 && c < ROWS) out[(long)(br + c) * TT + (TT - 1)] = pc;
  }
#undef STEP
}

extern "C" void kernel_launch(void* const* d_in, const int* in_sizes, int n_in,
                              void* d_out, int out_size, void* d_ws, size_t ws_size,
                              hipStream_t stream) {
  const float* x   = (const float*)d_in[0];
  // d_in[1] = labels (unused by the reference forward pass)
  const float* W1  = (const float*)d_in[2];
  const float* b1  = (const float*)d_in[3];
  const float* W2  = (const float*)d_in[4];
  const float* b2  = (const float*)d_in[5];
  float* out = (float*)d_out;

  ffnn_ar_kernel<<<512, 512, 0, stream>>>(x, W1, b1, W2, b2, out);
}

// Round 16
// 353.237 us; speedup vs baseline: 2.2198x; 2.2198x over previous
//
#include <hip/hip_runtime.h>

// Autoregressive FFNN. out[b,0]=0; t=1..511: mi=[x[b,t,:],pred]; h=relu(mi@W1+b1); pred=h@W2+b2.
// B=4096,T=512,F=63. 256 WGs x 512 thr (8 waves), 16 rows/WG, persistent (1 WG/CU is
// structural: weight-resident regs ~150+ incl AGPRs -> no co-residency possible; R12/R14).
// R15: SOFTWARE-PIPELINED step. VALU pred feedback => layer-1 MFMA depends only on x.
// Triple-buffered lds_A; at END of step t we issue layer-1 MFMAs for t+1 (tile staged at
// t-1), so they run during the barrier + next gather latency. Post-barrier critical path =
// gather -> z=acc+pc*w63 (packed f32x4 VALU) -> pack f16 -> 4 layer-2 MFMAs -> part write.
// Unroll-6 (3 A-bufs x 2 part-bufs) keeps all buffer indices compile-time.

#define TT 512
#define FF 63
#define HID 1024

typedef __attribute__((ext_vector_type(4))) float f32x4;
typedef __attribute__((ext_vector_type(4))) int i32x4;
typedef __attribute__((ext_vector_type(8))) _Float16 h16x8;

struct __attribute__((packed, aligned(4))) uf2 { float x, y; };

// LDS-visibility barrier WITHOUT the vmcnt(0) drain of __syncthreads.
__device__ __forceinline__ void lds_barrier() {
  asm volatile("s_waitcnt lgkmcnt(0)" ::: "memory");
  __builtin_amdgcn_s_barrier();
  asm volatile("" ::: "memory");
}

// pack a,b -> 2xf16 (RTZ, v_cvt_pkrtz_f16_f32) as int
__device__ __forceinline__ int pk2h(float a, float b) {
  auto h = __builtin_amdgcn_cvt_pkrtz(a, b);
  return __builtin_bit_cast(int, h);
}

__global__ __launch_bounds__(512, 2)
void ffnn_ar_kernel(const float* __restrict__ x,
                    const float* __restrict__ W1,
                    const float* __restrict__ b1,
                    const float* __restrict__ W2,
                    const float* __restrict__ b2p,
                    float* __restrict__ out) {
  __shared__ __align__(16) _Float16 lds_A[3][16][72];  // f16 x-tiles (col63 = 0), 3 bufs
  __shared__ __align__(16) float lds_part[2][16][12];  // [buf][batch c][wave w]

  const int tid  = threadIdx.x;
  const int lane = tid & 63;
  const int w    = tid >> 6;    // wave 0..7: hidden cols [128w, 128w+128)
  const int c    = lane & 15;   // batch column / frag row-id
  const int g    = lane >> 4;   // k-group
  const int br   = blockIdx.x * 16;
  const f32x4 zero4 = {0.f, 0.f, 0.f, 0.f};

  // ---- one-time weights ----
  h16x8 bfr[8][2];              // A1-frag = W1^T (f16); k=63 slot inert (col63=0 in tiles)
#pragma unroll
  for (int i = 0; i < 8; ++i) {
    const int n = (w * 8 + i) * 16 + c;
#pragma unroll
    for (int ks = 0; ks < 2; ++ks) {
      h16x8 f;
#pragma unroll
      for (int j = 0; j < 8; ++j) f[j] = (_Float16)W1[(ks * 32 + g * 8 + j) * HID + n];
      bfr[i][ks] = f;
    }
  }
  f32x4 b1v[8], w63v[8];        // C-init b1; VALU feedback weights W1[63]
#pragma unroll
  for (int i = 0; i < 8; ++i) {
    const int nb = (w * 8 + i) * 16 + g * 4;
    b1v[i]  = (f32x4){b1[nb], b1[nb + 1], b1[nb + 2], b1[nb + 3]};
    w63v[i] = (f32x4){W1[63 * HID + nb], W1[63 * HID + nb + 1],
                      W1[63 * HID + nb + 2], W1[63 * HID + nb + 3]};
  }
  h16x8 a2f[4];                 // layer-2 A-frags (replicated rows)
#pragma unroll
  for (int i2 = 0; i2 < 4; ++i2) {
    h16x8 f;
#pragma unroll
    for (int j = 0; j < 8; ++j)
      f[j] = (_Float16)W2[(w * 8 + 2 * i2 + (j >> 2)) * 16 + g * 4 + (j & 3)];
    a2f[i2] = f;
  }
  const float b2 = b2p[0];
  const float b2w = (w == 0) ? b2 : 0.f;

  // ---- x staging: 16 groups of 32 threads, one row each; packed 2 elems/lane ----
  const int srow = tid >> 5;
  const int sl   = tid & 31;    // lane31 packs (x62, 0) -> col63 = 0 every stage
  const long rowbase = (long)(br + srow) * (TT * FF);
  const bool full = (sl < 31);

  // prologue: stage x_1 -> buf1, x_2 -> buf2; zero part bufs; out[:,0]=0; prefetch x_3,x_4
  {
    float xa, xb2_;
    if (full) { const uf2 v = *reinterpret_cast<const uf2*>(&x[rowbase + FF + 2 * sl]); xa = v.x; xb2_ = v.y; }
    else      { xa = x[rowbase + FF + 62]; xb2_ = 0.f; }
    *reinterpret_cast<int*>(&lds_A[1][srow][2 * sl]) = pk2h(xa, xb2_);
    if (full) { const uf2 v = *reinterpret_cast<const uf2*>(&x[rowbase + 2 * FF + 2 * sl]); xa = v.x; xb2_ = v.y; }
    else      { xa = x[rowbase + 2 * FF + 62]; xb2_ = 0.f; }
    *reinterpret_cast<int*>(&lds_A[2][srow][2 * sl]) = pk2h(xa, xb2_);
  }
  if (tid < 384) reinterpret_cast<float*>(lds_part)[tid] = 0.f;
  if (tid < 16) out[(long)(br + tid) * TT] = 0.f;

  float s0a = 0.f, s0b = 0.f, s1a = 0.f, s1b = 0.f;
  if (full) {
    const uf2 v0 = *reinterpret_cast<const uf2*>(&x[rowbase + 3 * FF + 2 * sl]);
    const uf2 v1 = *reinterpret_cast<const uf2*>(&x[rowbase + 4 * FF + 2 * sl]);
    s0a = v0.x; s0b = v0.y; s1a = v1.x; s1b = v1.y;
  } else {
    s0a = x[rowbase + 3 * FF + 62];
    s1a = x[rowbase + 4 * FF + 62];
  }

  lds_barrier();

  // preload acc_1 from buf1 (x_1)
  f32x4 acc[8];
  {
    const h16x8 nx0 = *reinterpret_cast<const h16x8*>(&lds_A[1][c][g * 8]);
    const h16x8 nx1 = *reinterpret_cast<const h16x8*>(&lds_A[1][c][32 + g * 8]);
#pragma unroll
    for (int i = 0; i < 8; ++i) {
      f32x4 z4 = __builtin_amdgcn_mfma_f32_16x16x32_f16(bfr[i][0], nx0, b1v[i], 0, 0, 0);
      acc[i] = __builtin_amdgcn_mfma_f32_16x16x32_f16(bfr[i][1], nx1, z4, 0, 0, 0);
    }
  }

#define STEP(T, ARD, AWR, PRD, PWR, SA, SB)                                         \
  {                                                                                 \
    lds_barrier();                                                                  \
    /* gather pred_{T-1} (issued first; latency hidden by in-flight acc MFMAs) */   \
    const f32x4 v0 = *reinterpret_cast<const f32x4*>(&lds_part[PRD][c][0]);         \
    const f32x4 v1 = *reinterpret_cast<const f32x4*>(&lds_part[PRD][c][4]);         \
    /* x-frags for T+1 (staged at T-1, visible after this barrier) */               \
    const h16x8 nx0 = *reinterpret_cast<const h16x8*>(&lds_A[ARD][c][g * 8]);       \
    const h16x8 nx1 = *reinterpret_cast<const h16x8*>(&lds_A[ARD][c][32 + g * 8]);  \
    /* stage x_{T+2}; reload prefetch <- x_{T+4} (in flight across barriers) */     \
    *reinterpret_cast<int*>(&lds_A[AWR][srow][2 * sl]) = pk2h(SA, SB);              \
    {                                                                               \
      const int tp = ((T) + 4 < TT) ? (T) + 4 : TT - 1;                             \
      if (full) { const uf2 vv = *reinterpret_cast<const uf2*>(&x[rowbase + (long)tp * FF + 2 * sl]); \
                  SA = vv.x; SB = vv.y; }                                           \
      else      { SA = x[rowbase + (long)tp * FF + 62]; }                           \
    }                                                                               \
    const f32x4 sv = v0 + v1;                                                       \
    const float pc = (sv[0] + sv[1]) + (sv[2] + sv[3]);                             \
    if (w == 0 && g == 0) out[(long)(br + c) * TT + ((T) - 1)] = pc;                \
    const f32x4 pc4 = {pc, pc, pc, pc};                                             \
    /* epilogue on acc_T: z = acc + pc*w63 (pk_fma); relu (pk_max); pack; layer2 */ \
    f32x4 p2a = {b2w, b2w, b2w, b2w};                                               \
    f32x4 p2b = {0.f, 0.f, 0.f, 0.f};                                               \
    _Pragma("unroll") for (int i2 = 0; i2 < 4; ++i2) {                              \
      f32x4 zu = acc[2 * i2]     + pc4 * w63v[2 * i2];                              \
      f32x4 zv = acc[2 * i2 + 1] + pc4 * w63v[2 * i2 + 1];                          \
      zu = __builtin_elementwise_max(zu, zero4);                                    \
      zv = __builtin_elementwise_max(zv, zero4);                                    \
      const h16x8 hf = __builtin_bit_cast(h16x8, (i32x4){                           \
          pk2h(zu[0], zu[1]), pk2h(zu[2], zu[3]),                                   \
          pk2h(zv[0], zv[1]), pk2h(zv[2], zv[3])});                                 \
      if (i2 & 1)                                                                   \
        p2b = __builtin_amdgcn_mfma_f32_16x16x32_f16(a2f[i2], hf, p2b, 0, 0, 0);    \
      else                                                                          \
        p2a = __builtin_amdgcn_mfma_f32_16x16x32_f16(a2f[i2], hf, p2a, 0, 0, 0);    \
    }                                                                               \
    if (g == 0) lds_part[PWR][c][w] = p2a[0] + p2b[0];                              \
    /* issue layer-1 MFMAs for T+1 (run during barrier wait / next gather) */       \
    _Pragma("unroll") for (int i = 0; i < 8; ++i) {                                 \
      f32x4 z4 = __builtin_amdgcn_mfma_f32_16x16x32_f16(bfr[i][0], nx0, b1v[i], 0, 0, 0); \
      acc[i] = __builtin_amdgcn_mfma_f32_16x16x32_f16(bfr[i][1], nx1, z4, 0, 0, 0); \
    }                                                                               \
  }

#pragma unroll 1
  for (int t = 1; t + 5 < TT; t += 6) {   // t = 1,7,...,505 (t%6==1 -> const buf idx)
    STEP(t + 0, 2, 0, 0, 1, s0a, s0b)
    STEP(t + 1, 0, 1, 1, 0, s1a, s1b)
    STEP(t + 2, 1, 2, 0, 1, s0a, s0b)
    STEP(t + 3, 2, 0, 1, 0, s1a, s1b)
    STEP(t + 4, 0, 1, 0, 1, s0a, s0b)
    STEP(t + 5, 1, 2, 1, 0, s1a, s1b)
  }
  STEP(TT - 1, 2, 0, 0, 1, s0a, s0b)  // T = 511 (511 % 6 == 1; tail acc_512 unused)

  // final: pred_511 from lds_part[1]
  lds_barrier();
  {
    const f32x4 v0 = *reinterpret_cast<const f32x4*>(&lds_part[1][c][0]);
    const f32x4 v1 = *reinterpret_cast<const f32x4*>(&lds_part[1][c][4]);
    const f32x4 sv = v0 + v1;
    const float pc = (sv[0] + sv[1]) + (sv[2] + sv[3]);
    if (w == 0 && g == 0) out[(long)(br + c) * TT + (TT - 1)] = pc;
  }
#undef STEP
}

extern "C" void kernel_launch(void* const* d_in, const int* in_sizes, int n_in,
                              void* d_out, int out_size, void* d_ws, size_t ws_size,
                              hipStream_t stream) {
  const float* x   = (const float*)d_in[0];
  // d_in[1] = labels (unused by the reference forward pass)
  const float* W1  = (const float*)d_in[2];
  const float* b1  = (const float*)d_in[3];
  const float* W2  = (const float*)d_in[4];
  const float* b2  = (const float*)d_in[5];
  float* out = (float*)d_out;

  ffnn_ar_kernel<<<256, 512, 0, stream>>>(x, W1, b1, W2, b2, out);
}